// Round 15
// baseline (814.616 us; speedup 1.0000x reference)
//
#include <hip/hip_runtime.h>
#include <stdint.h>

typedef unsigned short u16;
typedef __attribute__((ext_vector_type(8))) __bf16 bf16x8;
typedef __attribute__((ext_vector_type(8))) unsigned short u16x8;
typedef __attribute__((ext_vector_type(4))) float f32x4;
typedef __attribute__((ext_vector_type(4))) unsigned int u32x4;

#define NREL 7
#define DIM  512
#define DEDGE 59
#define KC   420     // NREL*59 + NREL (weight-sum columns)
#define KCP  448     // padded to multiple of 32
#define KU   3584    // NREL*512 (node-path U region)
#define KTOT 4544    // KU + 512 (self, served from NF) + 448 (edge-G)

__device__ __forceinline__ float bf2f(u16 u) {
  union { unsigned u; float f; } c; c.u = ((unsigned)u) << 16; return c.f;
}
__device__ __forceinline__ u16 f2bf(float f) {
  union { float f; unsigned u; } c; c.f = f;
  unsigned r = ((c.u >> 16) & 1u) + 0x7FFFu;
  return (u16)((c.u + r) >> 16);
}

__device__ __forceinline__ void gload16(const void* g, void* l) {
  __builtin_amdgcn_global_load_lds(
      (__attribute__((address_space(1))) void*)g,
      (__attribute__((address_space(3))) void*)l, 16, 0, 0);
}

// ---- convert node_feat fp32 -> bf16 NF table [N,512] ----
__global__ void convA(const float* __restrict__ in, u16* __restrict__ out, int total4) {
  int i = blockIdx.x * 256 + threadIdx.x;
  if (i >= total4) return;
  float4 v = ((const float4*)in)[i];
  ushort4 r;
  r.x = f2bf(v.x); r.y = f2bf(v.y); r.z = f2bf(v.z); r.w = f2bf(v.w);
  ((ushort4*)out)[i] = r;
}

// ---- Bfull[o][k] bf16, [512][KTOT]: k<3584 -> W_lin[o][k]; 3584..4095 -> W_self[o][k-3584] ----
__global__ void buildBW(const float* __restrict__ W_lin, const float* __restrict__ W_self,
                        u16* __restrict__ Bfull, int total4) {
  int gid = blockIdx.x * 256 + threadIdx.x;
  if (gid >= total4) return;
  int idx = gid * 4;
  int o = idx >> 12;          // / 4096
  int k = idx & 4095;
  const float* src = (k < KU) ? (W_lin + (size_t)o * KU + k)
                              : (W_self + (size_t)o * DIM + (k - KU));
  float4 v = *(const float4*)src;
  ushort4 rr;
  rr.x = f2bf(v.x); rr.y = f2bf(v.y); rr.z = f2bf(v.z); rr.w = f2bf(v.w);
  *(ushort4*)(Bfull + (size_t)o * KTOT + k) = rr;
}

// ---- Bfull cols [4096, 4544): c=r*59+de -> sum_d W_edge[d,de]*W_lin[o,r*512+d];
//      c=413+r -> sum_d b_edge[d]*W_lin[o,r*512+d]; c>=420 -> 0 ----
__global__ __launch_bounds__(512) void buildCx(const float* __restrict__ W_edge,
                                               const float* __restrict__ b_edge,
                                               const float* __restrict__ W_lin,
                                               u16* __restrict__ Bfull) {
  int c = blockIdx.x;          // 0..447
  int o = threadIdx.x;         // 0..511
  u16* dst = Bfull + (size_t)o * KTOT + KU + DIM;  // col base 4096
  if (c >= KC) { dst[c] = 0; return; }
  __shared__ float col[DIM];
  int r;
  if (c < NREL * DEDGE) {
    r = c / DEDGE;
    int de = c - r * DEDGE;
    col[o] = W_edge[(size_t)o * DEDGE + de];
  } else {
    r = c - NREL * DEDGE;
    col[o] = b_edge[o];
  }
  __syncthreads();
  const float4* wv = (const float4*)(W_lin + (size_t)o * KU + (size_t)r * DIM);
  float acc = 0.f;
#pragma unroll 4
  for (int d4 = 0; d4 < DIM / 4; ++d4) {
    float4 wq = wv[d4];
    acc += col[d4 * 4 + 0] * wq.x + col[d4 * 4 + 1] * wq.y
         + col[d4 * 4 + 2] * wq.z + col[d4 * 4 + 3] * wq.w;
  }
  dst[c] = f2bf(acc);
}

// ---- two-level CSR keyed by (node_out, relation) ----
__global__ void countK2(const int* __restrict__ node_out, const int* __restrict__ relation,
                        int* __restrict__ counts2, int E) {
  int e = blockIdx.x * 256 + threadIdx.x;
  if (e < E) atomicAdd(&counts2[node_out[e] * 8 + relation[e]], 1);
}

// segment bases via atomic allocation — CSR segment ORDER is irrelevant (only
// disjointness matters), so no prefix scan needed.
__global__ void baseK(const int* __restrict__ counts2, int* __restrict__ offs2,
                      int* __restrict__ cursor2, int* __restrict__ totalCtr, int N) {
  int n = blockIdx.x * 256 + threadIdx.x;
  if (n >= N) return;
  int cnt[NREL];
  int s = 0;
#pragma unroll
  for (int r = 0; r < NREL; ++r) { cnt[r] = counts2[n * 8 + r]; s += cnt[r]; }
  int base = atomicAdd(totalCtr, s);
#pragma unroll
  for (int r = 0; r < NREL; ++r) {
    offs2[n * 8 + r] = base;
    cursor2[n * 8 + r] = base;
    base += cnt[r];
  }
  offs2[n * 8 + 7] = base;
}

// one 16B scattered store per edge: quad = (src, w_bits, e, 0)
__global__ void fillK2(const int* __restrict__ node_in, const int* __restrict__ node_out,
                       const int* __restrict__ relation, const float* __restrict__ ew,
                       int* __restrict__ cursor2, uint4* __restrict__ quads, int E) {
  int e = blockIdx.x * 256 + threadIdx.x;
  if (e >= E) return;
  int p = atomicAdd(&cursor2[node_out[e] * 8 + relation[e]], 1);
  quads[p] = make_uint4((unsigned)node_in[e], __float_as_uint(ew[e]), (unsigned)e, 0u);
}

// ---- edge-G aggregation (rel-segmented, atomic-free): G[n][0..448) ----
//      ef reads are compulsory HBM (151 MB table, no reuse); 20K waves give the MLP.
__global__ __launch_bounds__(64) void gatherG2(const float* __restrict__ ef,
                                               const uint4* __restrict__ quads,
                                               const int* __restrict__ offs2,
                                               u16* __restrict__ G) {
  int n = blockIdx.x;
  int lane = threadIdx.x;
  u16* grow = G + (size_t)n * KCP;
  int base = n * 8;
  for (int r = 0; r < NREL; ++r) {
    int p0 = offs2[base + r], p1 = offs2[base + r + 1];
    float acc = 0.f;
    for (int p = p0; p < p1; ++p) {
      uint4 q = quads[p];
      int e = __builtin_amdgcn_readfirstlane((int)q.z);
      float w = __uint_as_float(__builtin_amdgcn_readfirstlane(q.y));
      float v = (lane < DEDGE) ? ef[(size_t)e * DEDGE + lane] : 1.0f;
      acc += w * v;
    }
    if (lane < DEDGE) grow[r * DEDGE + lane] = f2bf(acc);
    else if (lane == DEDGE) grow[NREL * DEDGE + r] = f2bf(acc);
  }
  if (lane >= 60) {
    for (int c = KC + (lane - 60); c < KCP; c += 4) grow[c] = 0;
  }
}

// ---- node-path aggregation, ONE PASS (dp) over feature cols [dp*64, dp*64+64):
//      U[n][r*512+d] = sum w_e * NF[src_e][d].
//      Launched 8x serially — the kernel boundary is the device-wide phase barrier
//      that R12 lacked: within one launch every XCD's gather working set is ONE
//      2.56 MB NF column panel (< 4 MB/XCD L2), so the 635 MB of re-reads become
//      L2 hits. quads are nt-loaded and U nt-stored to keep the panel resident.
//      Block = 4 waves x 8 groups x 8 lanes; group owns one node; lane owns 8 cols
//      -> accumulators fully in-register, no cross-lane reduce (R12-verified). ----
__global__ __launch_bounds__(256) void aggP(const u16* __restrict__ NF,
                                            const uint4* __restrict__ quads,
                                            const int* __restrict__ offs2,
                                            u16* __restrict__ U, int N, int dp) {
  int wv = threadIdx.x >> 6, l = threadIdx.x & 63;
  int grp = l >> 3, gl = l & 7;         // group (node slot), lane-in-group
  int n = blockIdx.x * 32 + wv * 8 + grp;
  bool valid = n < N;
  int nn = valid ? n : N - 1;
  int c0 = dp * 64 + gl * 8;            // this lane's 8 feature cols
  // preload this node's offs2 row (8 ints, 32B) into registers
  const u32x4* orow = (const u32x4*)(offs2 + nn * 8);
  u32x4 oa = orow[0], ob = orow[1];
  int offr[8] = {(int)oa.x, (int)oa.y, (int)oa.z, (int)oa.w,
                 (int)ob.x, (int)ob.y, (int)ob.z, (int)ob.w};
  u16* ubase = U + (size_t)nn * KU + c0;
#pragma unroll
  for (int r = 0; r < NREL; ++r) {
    int p0 = offr[r], p1 = offr[r + 1];
    float a[8];
#pragma unroll
    for (int j = 0; j < 8; ++j) a[j] = 0.f;
    if (p0 < p1) {
      u32x4 q = __builtin_nontemporal_load((const u32x4*)(quads + p0));
      for (int p = p0; p < p1; ++p) {
        int pn = p + 1 < p1 ? p + 1 : p1 - 1;   // branchless clamp-prefetch
        u32x4 qn = __builtin_nontemporal_load((const u32x4*)(quads + pn));
        float w = __uint_as_float(q.y);
        int src = (int)q.x;
        u16x8 hv = *(const u16x8*)(NF + (size_t)src * DIM + c0);
#pragma unroll
        for (int j = 0; j < 8; ++j) a[j] += w * bf2f(hv[j]);
        q = qn;
      }
    }
    u16x8 st;
#pragma unroll
    for (int j = 0; j < 8; ++j) st[j] = f2bf(a[j]);
    if (valid)
      __builtin_nontemporal_store(st, (u16x8*)(ubase + (size_t)r * DIM));
  }
}

// ---- fused MFMA GEMM: out[M,512] = relu([U | NF | G] @ Bfull^T + b_lin + b_self)
//      A region-split: kt<112 -> U[M,3584]; 112..127 -> NF[M,512]; >=128 -> G[M,448].
//      R6 proven-best structure: T2 XOR bank-swizzle (conflicts=0), 3-buffer
//      counted-vmcnt pipeline, XCD panel-grouping swizzle, 128x128 block. ----
__global__ __launch_bounds__(256) void gemm_br(const u16* __restrict__ U,
                                               const u16* __restrict__ NF,
                                               const u16* __restrict__ G,
                                               const u16* __restrict__ Bt,
                                               const float* __restrict__ b_lin,
                                               const float* __restrict__ b_self,
                                               float* __restrict__ Cout, int M) {
  __shared__ __align__(16) u16 sA[3][128 * 32];
  __shared__ __align__(16) u16 sB[3][128 * 32];
  const int tid = threadIdx.x;
  const int w = tid >> 6, l = tid & 63;
  const int lr = l & 15, kg = l >> 4;
  const int sl = kg ^ ((lr >> 1) & 3);   // swizzled 16B-slot to read (lane-constant)

  const int id = blockIdx.x;
  const int npan = gridDim.x >> 2;
  const int nfull = (npan >> 3) << 3;
  int p, c;
  if (id < nfull * 4) {
    int g = id >> 5, r = id & 31;
    p = g * 8 + (r & 7);
    c = r >> 3;
  } else {
    int t = id - nfull * 4;
    p = nfull + (t >> 2);
    c = t & 3;
  }
  const int m0 = p * 128, n0 = c * 128;
  const int wr = w >> 1, wc = w & 1;
  f32x4 acc[4][4];
  const f32x4 z4 = {0.f, 0.f, 0.f, 0.f};
#pragma unroll
  for (int i = 0; i < 4; ++i)
#pragma unroll
    for (int j = 0; j < 4; ++j) acc[i][j] = z4;

  const int ktiles = KTOT / 32;   // 142

  auto stage = [&](int kt, int b) {
    const u16* Ab; int astr, ac0;
    if (kt < 112)      { Ab = U;  astr = KU;  ac0 = kt * 32; }
    else if (kt < 128) { Ab = NF; astr = DIM; ac0 = kt * 32 - KU; }
    else               { Ab = G;  astr = KCP; ac0 = kt * 32 - (KU + DIM); }
    const int k0 = kt * 32;
#pragma unroll
    for (int t = 0; t < 2; ++t) {
      int idx = w * 128 + t * 64 + l;     // 16B granule id within A tile (linear dest)
      int row = idx >> 2, kp = idx & 3;
      int s = kp ^ ((row >> 1) & 3);
      int gm = m0 + row; gm = gm < M ? gm : M - 1;
      gload16(Ab + (size_t)gm * astr + ac0 + s * 8,
              (char*)sA[b] + (size_t)idx * 16);
    }
#pragma unroll
    for (int t = 0; t < 2; ++t) {
      int idx = w * 128 + t * 64 + l;
      int row = idx >> 2, kp = idx & 3;
      int s = kp ^ ((row >> 1) & 3);
      gload16(Bt + (size_t)(n0 + row) * KTOT + k0 + s * 8,
              (char*)sB[b] + (size_t)idx * 16);
    }
  };

  stage(0, 0);
  stage(1, 1);
  asm volatile("s_waitcnt vmcnt(4)" ::: "memory");
  __builtin_amdgcn_s_barrier();
  __builtin_amdgcn_sched_barrier(0);

  for (int kt = 0; kt < ktiles; ++kt) {
    const int cur = kt % 3;
    if (kt + 2 < ktiles) stage(kt + 2, (kt + 2) % 3);
    bf16x8 af[4], bfr[4];
#pragma unroll
    for (int i = 0; i < 4; ++i)
      af[i] = *(const bf16x8*)(sA[cur] + (size_t)(wr * 64 + i * 16 + lr) * 32 + sl * 8);
#pragma unroll
    for (int j = 0; j < 4; ++j)
      bfr[j] = *(const bf16x8*)(sB[cur] + (size_t)(wc * 64 + j * 16 + lr) * 32 + sl * 8);
#pragma unroll
    for (int i = 0; i < 4; ++i)
#pragma unroll
      for (int j = 0; j < 4; ++j)
        acc[i][j] = __builtin_amdgcn_mfma_f32_16x16x32_bf16(af[i], bfr[j], acc[i][j], 0, 0, 0);
    if (kt + 2 < ktiles) {
      asm volatile("s_waitcnt vmcnt(4)" ::: "memory");
    } else {
      asm volatile("s_waitcnt vmcnt(0)" ::: "memory");
    }
    __builtin_amdgcn_s_barrier();
    __builtin_amdgcn_sched_barrier(0);
  }
#pragma unroll
  for (int i = 0; i < 4; ++i) {
#pragma unroll
    for (int j = 0; j < 4; ++j) {
      int gj = n0 + wc * 64 + j * 16 + lr;
      float bias = b_lin[gj] + b_self[gj];
#pragma unroll
      for (int v = 0; v < 4; ++v) {
        int gm = m0 + wr * 64 + i * 16 + kg * 4 + v;
        if (gm < M)
          ((float*)Cout)[(size_t)gm * DIM + gj] = fmaxf(acc[i][j][v] + bias, 0.f);
      }
    }
  }
}

extern "C" void kernel_launch(void* const* d_in, const int* in_sizes, int n_in,
                              void* d_out, int out_size, void* d_ws, size_t ws_size,
                              hipStream_t stream) {
  const float* node_feat = (const float*)d_in[0];
  const float* edge_weight = (const float*)d_in[1];
  const float* edge_feat = (const float*)d_in[2];
  const float* W_lin = (const float*)d_in[3];
  const float* b_lin = (const float*)d_in[4];
  const float* W_self = (const float*)d_in[5];
  const float* b_self = (const float*)d_in[6];
  const float* W_edge = (const float*)d_in[7];
  const float* b_edge = (const float*)d_in[8];
  const int* node_in = (const int*)d_in[9];
  const int* node_out = (const int*)d_in[10];
  const int* relation = (const int*)d_in[11];
  float* out = (float*)d_out;

  const int N = in_sizes[0] / DIM;
  const int E = in_sizes[1];

  char* ws = (char*)d_ws;
  size_t off = 0;
  auto take = [&](size_t b) {
    char* p = ws + off;
    off += (b + 255) & ~(size_t)255;
    return p;
  };
  u16* NF       = (u16*)take((size_t)N * DIM * 2);
  u16* Bfull    = (u16*)take((size_t)DIM * KTOT * 2);
  u16* U        = (u16*)take((size_t)N * KU * 2);
  u16* G        = (u16*)take((size_t)N * KCP * 2);
  int* counts2  = (int*)take((size_t)N * 8 * 4);
  int* offs2    = (int*)take((size_t)N * 8 * 4);
  int* cursor2  = (int*)take((size_t)N * 8 * 4);
  int* totalCtr = (int*)take(256);
  uint4* quads  = (uint4*)take((size_t)E * 16);
  if (off > ws_size) return;  // workspace too small — fail visibly via absmax

  hipMemsetAsync(counts2, 0, (size_t)N * 8 * 4, stream);
  hipMemsetAsync(totalCtr, 0, 256, stream);

  {
    int total4 = N * DIM / 4;
    convA<<<(total4 + 255) / 256, 256, 0, stream>>>(node_feat, NF, total4);
  }
  {
    int total4 = DIM * 4096 / 4;
    buildBW<<<(total4 + 255) / 256, 256, 0, stream>>>(W_lin, W_self, Bfull, total4);
  }
  buildCx<<<KCP, 512, 0, stream>>>(W_edge, b_edge, W_lin, Bfull);

  countK2<<<(E + 255) / 256, 256, 0, stream>>>(node_out, relation, counts2, E);
  baseK<<<(N + 255) / 256, 256, 0, stream>>>(counts2, offs2, cursor2, totalCtr, N);
  fillK2<<<(E + 255) / 256, 256, 0, stream>>>(node_in, node_out, relation, edge_weight,
                                              cursor2, quads, E);

  // edge-G (HBM-compulsory ef gather)
  gatherG2<<<N, 64, 0, stream>>>(edge_feat, quads, offs2, G);

  // node-path U: 8 pass-serialized launches — kernel boundary = device-wide phase
  // barrier, so each pass's 2.56 MB NF column panel stays L2-resident per XCD.
  {
    int nb = (N + 31) / 32;
    for (int dp = 0; dp < 8; ++dp)
      aggP<<<nb, 256, 0, stream>>>(NF, quads, offs2, U, N, dp);
  }

  // single fused GEMM + bias + relu (A = [U | NF | G] region-split; 1-D swizzled grid)
  {
    int npan = (N + 127) / 128;
    gemm_br<<<npan * 4, 256, 0, stream>>>(U, NF, G, Bfull, b_lin, b_self, out, N);
  }
}

// Round 16
// 497.149 us; speedup vs baseline: 1.6386x; 1.6386x over previous
//
#include <hip/hip_runtime.h>
#include <stdint.h>

typedef unsigned short u16;
typedef __attribute__((ext_vector_type(8))) __bf16 bf16x8;
typedef __attribute__((ext_vector_type(8))) unsigned short u16x8;
typedef __attribute__((ext_vector_type(4))) float f32x4;

#define NREL 7
#define DIM  512
#define DEDGE 59
#define KC   420     // NREL*59 + NREL (weight-sum columns)
#define KCP  448     // padded to multiple of 32
#define KU   3584    // NREL*512 (node-path U region)
#define KTOT 4544    // KU + 512 (self, served from NF) + 448 (edge-G)

__device__ __forceinline__ float bf2f(u16 u) {
  union { unsigned u; float f; } c; c.u = ((unsigned)u) << 16; return c.f;
}
__device__ __forceinline__ u16 f2bf(float f) {
  union { float f; unsigned u; } c; c.f = f;
  unsigned r = ((c.u >> 16) & 1u) + 0x7FFFu;
  return (u16)((c.u + r) >> 16);
}

__device__ __forceinline__ void gload16(const void* g, void* l) {
  __builtin_amdgcn_global_load_lds(
      (__attribute__((address_space(1))) void*)g,
      (__attribute__((address_space(3))) void*)l, 16, 0, 0);
}

// ---- convert node_feat fp32 -> bf16 NF table [N,512] ----
__global__ void convA(const float* __restrict__ in, u16* __restrict__ out, int total4) {
  int i = blockIdx.x * 256 + threadIdx.x;
  if (i >= total4) return;
  float4 v = ((const float4*)in)[i];
  ushort4 r;
  r.x = f2bf(v.x); r.y = f2bf(v.y); r.z = f2bf(v.z); r.w = f2bf(v.w);
  ((ushort4*)out)[i] = r;
}

// ---- Bfull[o][k] bf16, [512][KTOT]: k<3584 -> W_lin[o][k]; 3584..4095 -> W_self[o][k-3584] ----
__global__ void buildBW(const float* __restrict__ W_lin, const float* __restrict__ W_self,
                        u16* __restrict__ Bfull, int total4) {
  int gid = blockIdx.x * 256 + threadIdx.x;
  if (gid >= total4) return;
  int idx = gid * 4;
  int o = idx >> 12;          // / 4096
  int k = idx & 4095;
  const float* src = (k < KU) ? (W_lin + (size_t)o * KU + k)
                              : (W_self + (size_t)o * DIM + (k - KU));
  float4 v = *(const float4*)src;
  ushort4 rr;
  rr.x = f2bf(v.x); rr.y = f2bf(v.y); rr.z = f2bf(v.z); rr.w = f2bf(v.w);
  *(ushort4*)(Bfull + (size_t)o * KTOT + k) = rr;
}

// ---- Bfull cols [4096, 4544): c=r*59+de -> sum_d W_edge[d,de]*W_lin[o,r*512+d];
//      c=413+r -> sum_d b_edge[d]*W_lin[o,r*512+d]; c>=420 -> 0 ----
__global__ __launch_bounds__(512) void buildCx(const float* __restrict__ W_edge,
                                               const float* __restrict__ b_edge,
                                               const float* __restrict__ W_lin,
                                               u16* __restrict__ Bfull) {
  int c = blockIdx.x;          // 0..447
  int o = threadIdx.x;         // 0..511
  u16* dst = Bfull + (size_t)o * KTOT + KU + DIM;  // col base 4096
  if (c >= KC) { dst[c] = 0; return; }
  __shared__ float col[DIM];
  int r;
  if (c < NREL * DEDGE) {
    r = c / DEDGE;
    int de = c - r * DEDGE;
    col[o] = W_edge[(size_t)o * DEDGE + de];
  } else {
    r = c - NREL * DEDGE;
    col[o] = b_edge[o];
  }
  __syncthreads();
  const float4* wv = (const float4*)(W_lin + (size_t)o * KU + (size_t)r * DIM);
  float acc = 0.f;
#pragma unroll 4
  for (int d4 = 0; d4 < DIM / 4; ++d4) {
    float4 wq = wv[d4];
    acc += col[d4 * 4 + 0] * wq.x + col[d4 * 4 + 1] * wq.y
         + col[d4 * 4 + 2] * wq.z + col[d4 * 4 + 3] * wq.w;
  }
  dst[c] = f2bf(acc);
}

// ---- two-level CSR keyed by (node_out, relation) ----
__global__ void countK2(const int* __restrict__ node_out, const int* __restrict__ relation,
                        int* __restrict__ counts2, int E) {
  int e = blockIdx.x * 256 + threadIdx.x;
  if (e < E) atomicAdd(&counts2[node_out[e] * 8 + relation[e]], 1);
}

// segment bases via atomic allocation — CSR segment ORDER is irrelevant (only
// disjointness matters), so no prefix scan needed.
__global__ void baseK(const int* __restrict__ counts2, int* __restrict__ offs2,
                      int* __restrict__ cursor2, int* __restrict__ totalCtr, int N) {
  int n = blockIdx.x * 256 + threadIdx.x;
  if (n >= N) return;
  int cnt[NREL];
  int s = 0;
#pragma unroll
  for (int r = 0; r < NREL; ++r) { cnt[r] = counts2[n * 8 + r]; s += cnt[r]; }
  int base = atomicAdd(totalCtr, s);
#pragma unroll
  for (int r = 0; r < NREL; ++r) {
    offs2[n * 8 + r] = base;
    cursor2[n * 8 + r] = base;
    base += cnt[r];
  }
  offs2[n * 8 + 7] = base;
}

// one 16B scattered store per edge: quad = (src, w_bits, e, 0)
__global__ void fillK2(const int* __restrict__ node_in, const int* __restrict__ node_out,
                       const int* __restrict__ relation, const float* __restrict__ ew,
                       int* __restrict__ cursor2, uint4* __restrict__ quads, int E) {
  int e = blockIdx.x * 256 + threadIdx.x;
  if (e >= E) return;
  int p = atomicAdd(&cursor2[node_out[e] * 8 + relation[e]], 1);
  quads[p] = make_uint4((unsigned)node_in[e], __float_as_uint(ew[e]), (unsigned)e, 0u);
}

// ---- edge-G aggregation (rel-segmented, atomic-free): G[n][0..448).
//      4 nodes/block (one per wave) -> up to 32 waves/CU of TLP, and a depth-2/3
//      software pipeline (quads 3 ahead, ef 2 ahead, branchless clamp) so the
//      ef address for edge p+1 is known 2 iterations early — >=2 compulsory-HBM
//      ef loads stay in flight instead of one per ~1100-cy dependent chain. ----
__global__ __launch_bounds__(256) void gatherG2(const float* __restrict__ ef,
                                                const uint4* __restrict__ quads,
                                                const int* __restrict__ offs2,
                                                u16* __restrict__ G, int N) {
  int n = blockIdx.x * 4 + (threadIdx.x >> 6);
  int lane = threadIdx.x & 63;
  if (n >= N) return;
  u16* grow = G + (size_t)n * KCP;
  int base = n * 8;
  for (int r = 0; r < NREL; ++r) {
    int p0 = offs2[base + r], p1 = offs2[base + r + 1];
    float acc = 0.f;
    if (p0 < p1) {
      int pl = p1 - 1;
      int i1 = p0 + 1 < pl ? p0 + 1 : pl;
      int i2 = p0 + 2 < pl ? p0 + 2 : pl;
      uint4 q0 = quads[p0], q1 = quads[i1], q2 = quads[i2];
      float v0 = (lane < DEDGE) ? ef[(size_t)q0.z * DEDGE + lane] : 1.0f;
      float v1 = (lane < DEDGE) ? ef[(size_t)q1.z * DEDGE + lane] : 1.0f;
      for (int p = p0; p < p1; ++p) {
        int i3 = p + 3 < pl ? p + 3 : pl;        // branchless clamp-prefetch
        uint4 qn = quads[i3];
        float vn = (lane < DEDGE) ? ef[(size_t)q2.z * DEDGE + lane] : 1.0f;
        acc += __uint_as_float(q0.y) * v0;       // consume edge p
        q0 = q1; q1 = q2; q2 = qn;
        v0 = v1; v1 = vn;
      }
    }
    if (lane < DEDGE) grow[r * DEDGE + lane] = f2bf(acc);
    else if (lane == DEDGE) grow[NREL * DEDGE + r] = f2bf(acc);
  }
  if (lane >= 60) {
    for (int c = KC + (lane - 60); c < KCP; c += 4) grow[c] = 0;
  }
}

// ---- node-path aggregation (R9-proven best): one node/block, 4 waves
//      relation-parallel {wid, wid+4}; 64 lanes x u16x8 (full 1KB row per wave-read).
//      NF reads are L2/L3-BW-bound (~3.3 TB/s measured) — structural floor
//      (fusing, shfl-groups, pass-partitioning, pass-serialization all regressed). ----
__global__ __launch_bounds__(256) void aggK(const u16* __restrict__ NF,
                                            const uint4* __restrict__ quads,
                                            const int* __restrict__ offs2,
                                            u16* __restrict__ U) {
  int n = blockIdx.x;
  int wid = threadIdx.x >> 6, lane = threadIdx.x & 63;
  int o0 = lane * 8;
  u16* urow = U + (size_t)n * KU;
  int base = n * 8;
  for (int r = wid; r < NREL; r += 4) {
    int p0 = offs2[base + r], p1 = offs2[base + r + 1];
    float a[8];
#pragma unroll
    for (int j = 0; j < 8; ++j) a[j] = 0.f;
    for (int p = p0; p < p1; ++p) {
      uint4 q = quads[p];
      int src = __builtin_amdgcn_readfirstlane((int)q.x);
      float w = __uint_as_float(__builtin_amdgcn_readfirstlane(q.y));
      u16x8 hv = *(const u16x8*)(NF + (size_t)src * DIM + o0);
#pragma unroll
      for (int j = 0; j < 8; ++j) a[j] += w * bf2f(hv[j]);
    }
    u16x8 st;
#pragma unroll
    for (int j = 0; j < 8; ++j) st[j] = f2bf(a[j]);
    *(u16x8*)(urow + (size_t)r * DIM + o0) = st;
  }
}

// ---- fused MFMA GEMM: out[M,512] = relu([U | NF | G] @ Bfull^T + b_lin + b_self)
//      A region-split: kt<112 -> U[M,3584]; 112..127 -> NF[M,512]; >=128 -> G[M,448].
//      R6 proven-best structure: T2 XOR bank-swizzle (conflicts=0), 3-buffer
//      counted-vmcnt pipeline, XCD panel-grouping swizzle, 128x128 block. ----
__global__ __launch_bounds__(256) void gemm_br(const u16* __restrict__ U,
                                               const u16* __restrict__ NF,
                                               const u16* __restrict__ G,
                                               const u16* __restrict__ Bt,
                                               const float* __restrict__ b_lin,
                                               const float* __restrict__ b_self,
                                               float* __restrict__ Cout, int M) {
  __shared__ __align__(16) u16 sA[3][128 * 32];
  __shared__ __align__(16) u16 sB[3][128 * 32];
  const int tid = threadIdx.x;
  const int w = tid >> 6, l = tid & 63;
  const int lr = l & 15, kg = l >> 4;
  const int sl = kg ^ ((lr >> 1) & 3);   // swizzled 16B-slot to read (lane-constant)

  const int id = blockIdx.x;
  const int npan = gridDim.x >> 2;
  const int nfull = (npan >> 3) << 3;
  int p, c;
  if (id < nfull * 4) {
    int g = id >> 5, r = id & 31;
    p = g * 8 + (r & 7);
    c = r >> 3;
  } else {
    int t = id - nfull * 4;
    p = nfull + (t >> 2);
    c = t & 3;
  }
  const int m0 = p * 128, n0 = c * 128;
  const int wr = w >> 1, wc = w & 1;
  f32x4 acc[4][4];
  const f32x4 z4 = {0.f, 0.f, 0.f, 0.f};
#pragma unroll
  for (int i = 0; i < 4; ++i)
#pragma unroll
    for (int j = 0; j < 4; ++j) acc[i][j] = z4;

  const int ktiles = KTOT / 32;   // 142

  auto stage = [&](int kt, int b) {
    const u16* Ab; int astr, ac0;
    if (kt < 112)      { Ab = U;  astr = KU;  ac0 = kt * 32; }
    else if (kt < 128) { Ab = NF; astr = DIM; ac0 = kt * 32 - KU; }
    else               { Ab = G;  astr = KCP; ac0 = kt * 32 - (KU + DIM); }
    const int k0 = kt * 32;
#pragma unroll
    for (int t = 0; t < 2; ++t) {
      int idx = w * 128 + t * 64 + l;     // 16B granule id within A tile (linear dest)
      int row = idx >> 2, kp = idx & 3;
      int s = kp ^ ((row >> 1) & 3);
      int gm = m0 + row; gm = gm < M ? gm : M - 1;
      gload16(Ab + (size_t)gm * astr + ac0 + s * 8,
              (char*)sA[b] + (size_t)idx * 16);
    }
#pragma unroll
    for (int t = 0; t < 2; ++t) {
      int idx = w * 128 + t * 64 + l;
      int row = idx >> 2, kp = idx & 3;
      int s = kp ^ ((row >> 1) & 3);
      gload16(Bt + (size_t)(n0 + row) * KTOT + k0 + s * 8,
              (char*)sB[b] + (size_t)idx * 16);
    }
  };

  stage(0, 0);
  stage(1, 1);
  asm volatile("s_waitcnt vmcnt(4)" ::: "memory");
  __builtin_amdgcn_s_barrier();
  __builtin_amdgcn_sched_barrier(0);

  for (int kt = 0; kt < ktiles; ++kt) {
    const int cur = kt % 3;
    if (kt + 2 < ktiles) stage(kt + 2, (kt + 2) % 3);
    bf16x8 af[4], bfr[4];
#pragma unroll
    for (int i = 0; i < 4; ++i)
      af[i] = *(const bf16x8*)(sA[cur] + (size_t)(wr * 64 + i * 16 + lr) * 32 + sl * 8);
#pragma unroll
    for (int j = 0; j < 4; ++j)
      bfr[j] = *(const bf16x8*)(sB[cur] + (size_t)(wc * 64 + j * 16 + lr) * 32 + sl * 8);
#pragma unroll
    for (int i = 0; i < 4; ++i)
#pragma unroll
      for (int j = 0; j < 4; ++j)
        acc[i][j] = __builtin_amdgcn_mfma_f32_16x16x32_bf16(af[i], bfr[j], acc[i][j], 0, 0, 0);
    if (kt + 2 < ktiles) {
      asm volatile("s_waitcnt vmcnt(4)" ::: "memory");
    } else {
      asm volatile("s_waitcnt vmcnt(0)" ::: "memory");
    }
    __builtin_amdgcn_s_barrier();
    __builtin_amdgcn_sched_barrier(0);
  }
#pragma unroll
  for (int i = 0; i < 4; ++i) {
#pragma unroll
    for (int j = 0; j < 4; ++j) {
      int gj = n0 + wc * 64 + j * 16 + lr;
      float bias = b_lin[gj] + b_self[gj];
#pragma unroll
      for (int v = 0; v < 4; ++v) {
        int gm = m0 + wr * 64 + i * 16 + kg * 4 + v;
        if (gm < M)
          ((float*)Cout)[(size_t)gm * DIM + gj] = fmaxf(acc[i][j][v] + bias, 0.f);
      }
    }
  }
}

extern "C" void kernel_launch(void* const* d_in, const int* in_sizes, int n_in,
                              void* d_out, int out_size, void* d_ws, size_t ws_size,
                              hipStream_t stream) {
  const float* node_feat = (const float*)d_in[0];
  const float* edge_weight = (const float*)d_in[1];
  const float* edge_feat = (const float*)d_in[2];
  const float* W_lin = (const float*)d_in[3];
  const float* b_lin = (const float*)d_in[4];
  const float* W_self = (const float*)d_in[5];
  const float* b_self = (const float*)d_in[6];
  const float* W_edge = (const float*)d_in[7];
  const float* b_edge = (const float*)d_in[8];
  const int* node_in = (const int*)d_in[9];
  const int* node_out = (const int*)d_in[10];
  const int* relation = (const int*)d_in[11];
  float* out = (float*)d_out;

  const int N = in_sizes[0] / DIM;
  const int E = in_sizes[1];

  char* ws = (char*)d_ws;
  size_t off = 0;
  auto take = [&](size_t b) {
    char* p = ws + off;
    off += (b + 255) & ~(size_t)255;
    return p;
  };
  u16* NF       = (u16*)take((size_t)N * DIM * 2);
  u16* Bfull    = (u16*)take((size_t)DIM * KTOT * 2);
  u16* U        = (u16*)take((size_t)N * KU * 2);
  u16* G        = (u16*)take((size_t)N * KCP * 2);
  int* counts2  = (int*)take((size_t)N * 8 * 4);
  int* offs2    = (int*)take((size_t)N * 8 * 4);
  int* cursor2  = (int*)take((size_t)N * 8 * 4);
  int* totalCtr = (int*)take(256);
  uint4* quads  = (uint4*)take((size_t)E * 16);
  if (off > ws_size) return;  // workspace too small — fail visibly via absmax

  hipMemsetAsync(counts2, 0, (size_t)N * 8 * 4, stream);
  hipMemsetAsync(totalCtr, 0, 256, stream);

  {
    int total4 = N * DIM / 4;
    convA<<<(total4 + 255) / 256, 256, 0, stream>>>(node_feat, NF, total4);
  }
  {
    int total4 = DIM * 4096 / 4;
    buildBW<<<(total4 + 255) / 256, 256, 0, stream>>>(W_lin, W_self, Bfull, total4);
  }
  buildCx<<<KCP, 512, 0, stream>>>(W_edge, b_edge, W_lin, Bfull);

  countK2<<<(E + 255) / 256, 256, 0, stream>>>(node_out, relation, counts2, E);
  baseK<<<(N + 255) / 256, 256, 0, stream>>>(counts2, offs2, cursor2, totalCtr, N);
  fillK2<<<(E + 255) / 256, 256, 0, stream>>>(node_in, node_out, relation, edge_weight,
                                              cursor2, quads, E);

  // edge-G (HBM-compulsory ef gather, pipelined), then node-path U (L3-BW-bound)
  gatherG2<<<(N + 3) / 4, 256, 0, stream>>>(edge_feat, quads, offs2, G, N);
  aggK<<<N, 256, 0, stream>>>(NF, quads, offs2, U);

  // single fused GEMM + bias + relu (A = [U | NF | G] region-split; 1-D swizzled grid)
  {
    int npan = (N + 127) / 128;
    gemm_br<<<npan * 4, 256, 0, stream>>>(U, NF, G, Bfull, b_lin, b_self, out, N);
  }
}

// Round 17
// 454.640 us; speedup vs baseline: 1.7918x; 1.0935x over previous
//
#include <hip/hip_runtime.h>
#include <stdint.h>

typedef unsigned short u16;
typedef __attribute__((ext_vector_type(8))) __bf16 bf16x8;
typedef __attribute__((ext_vector_type(8))) unsigned short u16x8;
typedef __attribute__((ext_vector_type(4))) float f32x4;

#define NREL 7
#define DIM  512
#define DEDGE 59
#define KC   420     // NREL*59 + NREL (weight-sum columns)
#define KCP  448     // padded to multiple of 32
#define KU   3584    // NREL*512 (node-path U region)
#define KTOT 4544    // KU + 512 (self, served from NF) + 448 (edge-G)

__device__ __forceinline__ float bf2f(u16 u) {
  union { unsigned u; float f; } c; c.u = ((unsigned)u) << 16; return c.f;
}
__device__ __forceinline__ u16 f2bf(float f) {
  union { float f; unsigned u; } c; c.f = f;
  unsigned r = ((c.u >> 16) & 1u) + 0x7FFFu;
  return (u16)((c.u + r) >> 16);
}

__device__ __forceinline__ void gload16(const void* g, void* l) {
  __builtin_amdgcn_global_load_lds(
      (__attribute__((address_space(1))) void*)g,
      (__attribute__((address_space(3))) void*)l, 16, 0, 0);
}

// ---- MERGED prep: region A convA (fp32->bf16 NF), region B buildBW (W_lin|W_self
//      -> Bfull cols [0,4096)), region C countK2 (CSR histogram), region D zero
//      Bfull pad cols [4096+420, 4096+448). All four are mutually independent. ----
__global__ __launch_bounds__(256) void prep1(const float* __restrict__ nf_in,
                                             u16* __restrict__ NF,
                                             const float* __restrict__ W_lin,
                                             const float* __restrict__ W_self,
                                             u16* __restrict__ Bfull,
                                             const int* __restrict__ node_out,
                                             const int* __restrict__ relation,
                                             int* __restrict__ counts2,
                                             int totalA4, int bA, int bB, int bC, int E) {
  int bid = blockIdx.x;
  int t = threadIdx.x;
  if (bid < bA) {
    // convA
    int i = bid * 256 + t;
    if (i >= totalA4) return;
    float4 v = ((const float4*)nf_in)[i];
    ushort4 r;
    r.x = f2bf(v.x); r.y = f2bf(v.y); r.z = f2bf(v.z); r.w = f2bf(v.w);
    ((ushort4*)NF)[i] = r;
  } else if (bid < bB) {
    // buildBW (total 524288 gid = 2048 blocks exactly)
    int gid = (bid - bA) * 256 + t;
    int idx = gid * 4;
    int o = idx >> 12;          // / 4096
    int k = idx & 4095;
    const float* src = (k < KU) ? (W_lin + (size_t)o * KU + k)
                                : (W_self + (size_t)o * DIM + (k - KU));
    float4 v = *(const float4*)src;
    ushort4 rr;
    rr.x = f2bf(v.x); rr.y = f2bf(v.y); rr.z = f2bf(v.z); rr.w = f2bf(v.w);
    *(ushort4*)(Bfull + (size_t)o * KTOT + k) = rr;
  } else if (bid < bC) {
    // countK2
    int e = (bid - bB) * 256 + t;
    if (e < E) atomicAdd(&counts2[node_out[e] * 8 + relation[e]], 1);
  } else {
    // zero Bfull pad cols [KC, KCP) of the edge-G region
    int idx = (bid - bC) * 256 + t;
    if (idx < DIM * (KCP - KC)) {
      int o = idx / (KCP - KC), c = idx - o * (KCP - KC);
      Bfull[(size_t)o * KTOT + KU + DIM + KC + c] = 0;
    }
  }
}

// ---- Bfull cols [4096, 4544), 8 columns per block with W_lin-row reuse:
//      block (r, chunk): stages 8 col-vectors (W_edge cols / b_edge) in LDS,
//      each thread o reads its W_lin row ONCE (float4) and dots against all 8.
//      Cuts W_lin re-reads 8x vs one-column-per-block (470 MB -> 59 MB). ----
__global__ __launch_bounds__(512) void buildCx8(const float* __restrict__ W_edge,
                                                const float* __restrict__ b_edge,
                                                const float* __restrict__ W_lin,
                                                u16* __restrict__ Bfull) {
  __shared__ __align__(16) float cols[DIM][8];
  int r = blockIdx.x >> 3, chunk = blockIdx.x & 7;
  int o = threadIdx.x;
#pragma unroll
  for (int s = 0; s < 8; ++s) {
    int de = chunk * 8 + s;
    float v = 0.f;
    if (de < DEDGE) v = W_edge[(size_t)o * DEDGE + de];
    else if (de == DEDGE) v = b_edge[o];
    cols[o][s] = v;
  }
  __syncthreads();
  const float4* wv = (const float4*)(W_lin + (size_t)o * KU + (size_t)r * DIM);
  float acc[8];
#pragma unroll
  for (int s = 0; s < 8; ++s) acc[s] = 0.f;
  for (int d4 = 0; d4 < DIM / 4; ++d4) {
    float4 wq = wv[d4];
#pragma unroll
    for (int dd = 0; dd < 4; ++dd) {
      float wqd = (dd == 0) ? wq.x : (dd == 1) ? wq.y : (dd == 2) ? wq.z : wq.w;
      const float4* cp = (const float4*)&cols[d4 * 4 + dd][0];   // broadcast reads
      float4 c0 = cp[0], c1 = cp[1];
      acc[0] += wqd * c0.x; acc[1] += wqd * c0.y;
      acc[2] += wqd * c0.z; acc[3] += wqd * c0.w;
      acc[4] += wqd * c1.x; acc[5] += wqd * c1.y;
      acc[6] += wqd * c1.z; acc[7] += wqd * c1.w;
    }
  }
  u16* dst = Bfull + (size_t)o * KTOT + KU + DIM;
#pragma unroll
  for (int s = 0; s < 8; ++s) {
    int de = chunk * 8 + s;
    if (de < DEDGE) dst[(size_t)r * DEDGE + de] = f2bf(acc[s]);
    else if (de == DEDGE) dst[NREL * DEDGE + r] = f2bf(acc[s]);
  }
}

// segment bases via atomic allocation — CSR segment ORDER is irrelevant (only
// disjointness matters), so no prefix scan needed.
__global__ void baseK(const int* __restrict__ counts2, int* __restrict__ offs2,
                      int* __restrict__ cursor2, int* __restrict__ totalCtr, int N) {
  int n = blockIdx.x * 256 + threadIdx.x;
  if (n >= N) return;
  int cnt[NREL];
  int s = 0;
#pragma unroll
  for (int r = 0; r < NREL; ++r) { cnt[r] = counts2[n * 8 + r]; s += cnt[r]; }
  int base = atomicAdd(totalCtr, s);
#pragma unroll
  for (int r = 0; r < NREL; ++r) {
    offs2[n * 8 + r] = base;
    cursor2[n * 8 + r] = base;
    base += cnt[r];
  }
  offs2[n * 8 + 7] = base;
}

// one 16B scattered store per edge: quad = (src, w_bits, e, 0)
__global__ void fillK2(const int* __restrict__ node_in, const int* __restrict__ node_out,
                       const int* __restrict__ relation, const float* __restrict__ ew,
                       int* __restrict__ cursor2, uint4* __restrict__ quads, int E) {
  int e = blockIdx.x * 256 + threadIdx.x;
  if (e >= E) return;
  int p = atomicAdd(&cursor2[node_out[e] * 8 + relation[e]], 1);
  quads[p] = make_uint4((unsigned)node_in[e], __float_as_uint(ew[e]), (unsigned)e, 0u);
}

// ---- edge-G aggregation (R14-proven best: one node/block, 64 threads, plain
//      quad broadcast). ef reads are compulsory HBM (151 MB, no reuse); 20K waves
//      give the MLP. Pipelining/prefetch variants all regressed (R15/R16). ----
__global__ __launch_bounds__(64) void gatherG2(const float* __restrict__ ef,
                                               const uint4* __restrict__ quads,
                                               const int* __restrict__ offs2,
                                               u16* __restrict__ G) {
  int n = blockIdx.x;
  int lane = threadIdx.x;
  u16* grow = G + (size_t)n * KCP;
  int base = n * 8;
  for (int r = 0; r < NREL; ++r) {
    int p0 = offs2[base + r], p1 = offs2[base + r + 1];
    float acc = 0.f;
    for (int p = p0; p < p1; ++p) {
      uint4 q = quads[p];
      int e = __builtin_amdgcn_readfirstlane((int)q.z);
      float w = __uint_as_float(__builtin_amdgcn_readfirstlane(q.y));
      float v = (lane < DEDGE) ? ef[(size_t)e * DEDGE + lane] : 1.0f;
      acc += w * v;
    }
    if (lane < DEDGE) grow[r * DEDGE + lane] = f2bf(acc);
    else if (lane == DEDGE) grow[NREL * DEDGE + r] = f2bf(acc);
  }
  if (lane >= 60) {
    for (int c = KC + (lane - 60); c < KCP; c += 4) grow[c] = 0;
  }
}

// ---- node-path aggregation (R9-proven best): one node/block, 4 waves
//      relation-parallel {wid, wid+4}; 64 lanes x u16x8 (full 1KB row per wave-read).
//      NF reads are L2/L3-BW-bound (~3.3 TB/s measured) — structural floor. ----
__global__ __launch_bounds__(256) void aggK(const u16* __restrict__ NF,
                                            const uint4* __restrict__ quads,
                                            const int* __restrict__ offs2,
                                            u16* __restrict__ U) {
  int n = blockIdx.x;
  int wid = threadIdx.x >> 6, lane = threadIdx.x & 63;
  int o0 = lane * 8;
  u16* urow = U + (size_t)n * KU;
  int base = n * 8;
  for (int r = wid; r < NREL; r += 4) {
    int p0 = offs2[base + r], p1 = offs2[base + r + 1];
    float a[8];
#pragma unroll
    for (int j = 0; j < 8; ++j) a[j] = 0.f;
    for (int p = p0; p < p1; ++p) {
      uint4 q = quads[p];
      int src = __builtin_amdgcn_readfirstlane((int)q.x);
      float w = __uint_as_float(__builtin_amdgcn_readfirstlane(q.y));
      u16x8 hv = *(const u16x8*)(NF + (size_t)src * DIM + o0);
#pragma unroll
      for (int j = 0; j < 8; ++j) a[j] += w * bf2f(hv[j]);
    }
    u16x8 st;
#pragma unroll
    for (int j = 0; j < 8; ++j) st[j] = f2bf(a[j]);
    *(u16x8*)(urow + (size_t)r * DIM + o0) = st;
  }
}

// ---- fused MFMA GEMM: out[M,512] = relu([U | NF | G] @ Bfull^T + b_lin + b_self)
//      A region-split: kt<112 -> U[M,3584]; 112..127 -> NF[M,512]; >=128 -> G[M,448].
//      R6 proven-best structure: T2 XOR bank-swizzle (conflicts=0), 3-buffer
//      counted-vmcnt pipeline, XCD panel-grouping swizzle, 128x128 block. ----
__global__ __launch_bounds__(256) void gemm_br(const u16* __restrict__ U,
                                               const u16* __restrict__ NF,
                                               const u16* __restrict__ G,
                                               const u16* __restrict__ Bt,
                                               const float* __restrict__ b_lin,
                                               const float* __restrict__ b_self,
                                               float* __restrict__ Cout, int M) {
  __shared__ __align__(16) u16 sA[3][128 * 32];
  __shared__ __align__(16) u16 sB[3][128 * 32];
  const int tid = threadIdx.x;
  const int w = tid >> 6, l = tid & 63;
  const int lr = l & 15, kg = l >> 4;
  const int sl = kg ^ ((lr >> 1) & 3);   // swizzled 16B-slot to read (lane-constant)

  const int id = blockIdx.x;
  const int npan = gridDim.x >> 2;
  const int nfull = (npan >> 3) << 3;
  int p, c;
  if (id < nfull * 4) {
    int g = id >> 5, r = id & 31;
    p = g * 8 + (r & 7);
    c = r >> 3;
  } else {
    int t = id - nfull * 4;
    p = nfull + (t >> 2);
    c = t & 3;
  }
  const int m0 = p * 128, n0 = c * 128;
  const int wr = w >> 1, wc = w & 1;
  f32x4 acc[4][4];
  const f32x4 z4 = {0.f, 0.f, 0.f, 0.f};
#pragma unroll
  for (int i = 0; i < 4; ++i)
#pragma unroll
    for (int j = 0; j < 4; ++j) acc[i][j] = z4;

  const int ktiles = KTOT / 32;   // 142

  auto stage = [&](int kt, int b) {
    const u16* Ab; int astr, ac0;
    if (kt < 112)      { Ab = U;  astr = KU;  ac0 = kt * 32; }
    else if (kt < 128) { Ab = NF; astr = DIM; ac0 = kt * 32 - KU; }
    else               { Ab = G;  astr = KCP; ac0 = kt * 32 - (KU + DIM); }
    const int k0 = kt * 32;
#pragma unroll
    for (int t = 0; t < 2; ++t) {
      int idx = w * 128 + t * 64 + l;     // 16B granule id within A tile (linear dest)
      int row = idx >> 2, kp = idx & 3;
      int s = kp ^ ((row >> 1) & 3);
      int gm = m0 + row; gm = gm < M ? gm : M - 1;
      gload16(Ab + (size_t)gm * astr + ac0 + s * 8,
              (char*)sA[b] + (size_t)idx * 16);
    }
#pragma unroll
    for (int t = 0; t < 2; ++t) {
      int idx = w * 128 + t * 64 + l;
      int row = idx >> 2, kp = idx & 3;
      int s = kp ^ ((row >> 1) & 3);
      gload16(Bt + (size_t)(n0 + row) * KTOT + k0 + s * 8,
              (char*)sB[b] + (size_t)idx * 16);
    }
  };

  stage(0, 0);
  stage(1, 1);
  asm volatile("s_waitcnt vmcnt(4)" ::: "memory");
  __builtin_amdgcn_s_barrier();
  __builtin_amdgcn_sched_barrier(0);

  for (int kt = 0; kt < ktiles; ++kt) {
    const int cur = kt % 3;
    if (kt + 2 < ktiles) stage(kt + 2, (kt + 2) % 3);
    bf16x8 af[4], bfr[4];
#pragma unroll
    for (int i = 0; i < 4; ++i)
      af[i] = *(const bf16x8*)(sA[cur] + (size_t)(wr * 64 + i * 16 + lr) * 32 + sl * 8);
#pragma unroll
    for (int j = 0; j < 4; ++j)
      bfr[j] = *(const bf16x8*)(sB[cur] + (size_t)(wc * 64 + j * 16 + lr) * 32 + sl * 8);
#pragma unroll
    for (int i = 0; i < 4; ++i)
#pragma unroll
      for (int j = 0; j < 4; ++j)
        acc[i][j] = __builtin_amdgcn_mfma_f32_16x16x32_bf16(af[i], bfr[j], acc[i][j], 0, 0, 0);
    if (kt + 2 < ktiles) {
      asm volatile("s_waitcnt vmcnt(4)" ::: "memory");
    } else {
      asm volatile("s_waitcnt vmcnt(0)" ::: "memory");
    }
    __builtin_amdgcn_s_barrier();
    __builtin_amdgcn_sched_barrier(0);
  }
#pragma unroll
  for (int i = 0; i < 4; ++i) {
#pragma unroll
    for (int j = 0; j < 4; ++j) {
      int gj = n0 + wc * 64 + j * 16 + lr;
      float bias = b_lin[gj] + b_self[gj];
#pragma unroll
      for (int v = 0; v < 4; ++v) {
        int gm = m0 + wr * 64 + i * 16 + kg * 4 + v;
        if (gm < M)
          ((float*)Cout)[(size_t)gm * DIM + gj] = fmaxf(acc[i][j][v] + bias, 0.f);
      }
    }
  }
}

extern "C" void kernel_launch(void* const* d_in, const int* in_sizes, int n_in,
                              void* d_out, int out_size, void* d_ws, size_t ws_size,
                              hipStream_t stream) {
  const float* node_feat = (const float*)d_in[0];
  const float* edge_weight = (const float*)d_in[1];
  const float* edge_feat = (const float*)d_in[2];
  const float* W_lin = (const float*)d_in[3];
  const float* b_lin = (const float*)d_in[4];
  const float* W_self = (const float*)d_in[5];
  const float* b_self = (const float*)d_in[6];
  const float* W_edge = (const float*)d_in[7];
  const float* b_edge = (const float*)d_in[8];
  const int* node_in = (const int*)d_in[9];
  const int* node_out = (const int*)d_in[10];
  const int* relation = (const int*)d_in[11];
  float* out = (float*)d_out;

  const int N = in_sizes[0] / DIM;
  const int E = in_sizes[1];

  char* ws = (char*)d_ws;
  size_t off = 0;
  auto take = [&](size_t b) {
    char* p = ws + off;
    off += (b + 255) & ~(size_t)255;
    return p;
  };
  u16* NF       = (u16*)take((size_t)N * DIM * 2);
  u16* Bfull    = (u16*)take((size_t)DIM * KTOT * 2);
  u16* U        = (u16*)take((size_t)N * KU * 2);
  u16* G        = (u16*)take((size_t)N * KCP * 2);
  int* counts2  = (int*)take((size_t)N * 8 * 4);
  int* offs2    = (int*)take((size_t)N * 8 * 4);
  int* cursor2  = (int*)take((size_t)N * 8 * 4);
  int* totalCtr = (int*)take(256);
  uint4* quads  = (uint4*)take((size_t)E * 16);
  if (off > ws_size) return;  // workspace too small — fail visibly via absmax

  hipMemsetAsync(counts2, 0, (size_t)N * 8 * 4, stream);
  hipMemsetAsync(totalCtr, 0, 256, stream);

  // merged prep: convA | buildBW | countK2 | Bfull-pad-zero
  {
    int totalA4 = N * DIM / 4;
    int bA = (totalA4 + 255) / 256;            // convA blocks
    int bB = bA + (DIM * 4096 / 4) / 256;      // + buildBW blocks (exact)
    int bC = bB + (E + 255) / 256;             // + countK2 blocks
    int bD = bC + (DIM * (KCP - KC) + 255) / 256;  // + pad-zero blocks
    prep1<<<bD, 256, 0, stream>>>(node_feat, NF, W_lin, W_self, Bfull,
                                  node_out, relation, counts2,
                                  totalA4, bA, bB, bC, E);
  }
  // Bfull edge-G columns (8 cols/block, W_lin-row reuse)
  buildCx8<<<NREL * 8, 512, 0, stream>>>(W_edge, b_edge, W_lin, Bfull);

  baseK<<<(N + 255) / 256, 256, 0, stream>>>(counts2, offs2, cursor2, totalCtr, N);
  fillK2<<<(E + 255) / 256, 256, 0, stream>>>(node_in, node_out, relation, edge_weight,
                                              cursor2, quads, E);

  // edge-G (HBM-compulsory ef gather), then node-path U (L3-BW-bound) — separate,
  // serial, simple: measured best (R10-R16 variants all regressed)
  gatherG2<<<N, 64, 0, stream>>>(edge_feat, quads, offs2, G);
  aggK<<<N, 256, 0, stream>>>(NF, quads, offs2, U);

  // single fused GEMM + bias + relu (A = [U | NF | G] region-split; 1-D swizzled grid)
  {
    int npan = (N + 127) / 128;
    gemm_br<<<npan * 4, 256, 0, stream>>>(U, NF, G, Bfull, b_lin, b_self, out, N);
  }
}